// Round 2
// baseline (298.588 us; speedup 1.0000x reference)
//
#include <hip/hip_runtime.h>
#include <math.h>

#define NN   10000
#define DEG  16
#define SS   128
#define NRBF 20
#define GG   64
#define RC   10.0f
#define PI_F 3.14159265358979323846f
#define NB   8

__device__ __forceinline__ float silu_f(float x){
    return x / (1.0f + __expf(-x));
}

// swizzled LDS index for [row][node] tiles (row stride 8, XOR-swizzle on node)
__device__ __forceinline__ int lidx(int i, int b){
    return (i << 3) | ((b ^ i) & 7);
}

// ---------------------------------------------------------------------------
// Kernel 1: phi (uniform across edges since state is broadcast at round 0)
// Also zeroes the graph accumulator.
// ---------------------------------------------------------------------------
__global__ __launch_bounds__(128) void k_phi(
    const float* __restrict__ emb0,
    const float* __restrict__ w1, const float* __restrict__ b1,
    const float* __restrict__ w2, const float* __restrict__ b2,
    float* __restrict__ phiW, float* __restrict__ gs){
    __shared__ float s0[SS];
    __shared__ float hL[SS];
    int t = threadIdx.x;
    for (int i = t; i < GG*SS; i += 128) gs[i] = 0.0f;
    s0[t] = 128.0f * emb0[t];
    __syncthreads();
    float acc = b1[t];
    for (int s = 0; s < SS; s++) acc = fmaf(s0[s], w1[s*SS + t], acc);
    hL[t] = silu_f(acc);
    __syncthreads();
    for (int c = t; c < 3*SS; c += 128){
        float a = b2[c];
        for (int j = 0; j < SS; j++) a = fmaf(hL[j], w2[j*3*SS + c], a);
        phiW[c] = a;
    }
}

// ---------------------------------------------------------------------------
// Kernel 2: per-node edge processing. Block n handles edges [16n, 16n+16).
// 128 threads; thread t computes BOTH channel 128+t (m2 -> state) and
// channel 256+t (m3 -> sv), sharing the rbf LDS reads between them.
// Channels 0..S (m1) are skipped: state_vec is zero at round 0.
// ---------------------------------------------------------------------------
__global__ __launch_bounds__(128) void k_edge(
    const float* __restrict__ evd, const float* __restrict__ elen,
    const int* __restrict__ node_from,
    const float* __restrict__ filt_w, const float* __restrict__ filt_b,
    const float* __restrict__ phiW,
    float* __restrict__ state, float* __restrict__ sv){
    __shared__ float rS[DEG];            // r_safe
    __shared__ float mcL[DEG];           // mask * cutoff
    __shared__ float frL[DEG];           // mask * r^2
    __shared__ float eV[DEG][3];
    __shared__ float rbfL[DEG][NRBF];    // 80B rows, 16B aligned
    __shared__ float invD;
    int n = blockIdx.x;
    int t = threadIdx.x;

    if (t < DEG){
        int e = n*DEG + t;
        float x = evd[3*e+0], y = evd[3*e+1], z = evd[3*e+2];
        float r = sqrtf(x*x + y*y + z*z);
        float len  = elen[e];
        float mask = (fabsf(len) <= RC) ? 1.0f : 0.0f;
        float cut  = (r < RC) ? 0.5f*(cosf(PI_F*r*(1.0f/RC)) + 1.0f) : 0.0f;
        rS[t]  = fmaxf(r, 1e-12f);
        mcL[t] = mask * cut;
        frL[t] = mask * r * r;
        eV[t][0] = x; eV[t][1] = y; eV[t][2] = z;
    }
    __syncthreads();
    for (int idx = t; idx < DEG*NRBF; idx += 128){
        int e = idx / NRBF, k = idx % NRBF;
        float rs = rS[e];
        rbfL[e][k] = sinf((float)(k+1) * (PI_F/RC) * rs) / rs;
    }
    if (t == 0){
        float s = 0.0f;
        for (int e = 0; e < DEG; e++) s += frL[e];
        float fbn = sqrtf(s);
        invD = (fbn > 0.0f) ? 1.0f/fbn : 1.0f;
    }
    __syncthreads();

    int gc1 = SS + t;      // m2 channel
    int gc2 = 2*SS + t;    // m3 channel
    float fw1[NRBF], fw2[NRBF];
    #pragma unroll
    for (int k = 0; k < NRBF; k++){
        fw1[k] = filt_w[k*(3*SS) + gc1];
        fw2[k] = filt_w[k*(3*SS) + gc2];
    }
    float fb1 = filt_b[gc1], fb2 = filt_b[gc2];
    float ph1 = phiW[gc1],   ph2 = phiW[gc2];
    float iD  = invD;
    int   s3  = t % 3;

    float acc1 = 0.0f, acc2 = 0.0f;
    for (int e = 0; e < DEG; e++){
        float mc = mcL[e];
        if (mc == 0.0f) continue;   // wave-uniform skip (mask=0 or r>=RC)
        const float4* rv = (const float4*)(&rbfL[e][0]);
        float4 r0 = rv[0], r1 = rv[1], r2 = rv[2], r3 = rv[3], r4 = rv[4];
        float rr[20] = {r0.x,r0.y,r0.z,r0.w, r1.x,r1.y,r1.z,r1.w,
                        r2.x,r2.y,r2.z,r2.w, r3.x,r3.y,r3.z,r3.w,
                        r4.x,r4.y,r4.z,r4.w};
        float w1 = fb1, w2 = fb2;
        #pragma unroll
        for (int k = 0; k < NRBF; k++){
            w1 = fmaf(rr[k], fw1[k], w1);
            w2 = fmaf(rr[k], fw2[k], w2);
        }
        acc1 = fmaf(ph1*mc, w1, acc1);
        acc2 = fmaf(ph2*mc*eV[e][s3]*iD, w2, acc2);
    }
    int nf = node_from[n*DEG];
    state[nf*SS + t] = acc1;
    sv[nf*SS + t]    = acc2;
}

// ---------------------------------------------------------------------------
// Kernel 3: per-node update, NB=8 nodes per 128-thread block.
// Thread layout: b = t&7 (node), q = t>>3, channels c0=q*8 .. c0+7.
// x-operands come from LDS as single b32 reads (8 distinct addrs, dedup'd);
// weights as float4 pairs (8-way same-address lane dedup).
// ---------------------------------------------------------------------------
__global__ __launch_bounds__(128) void k_update(
    const float* __restrict__ state, const float* __restrict__ sv,
    const float* __restrict__ u_w, const float* __restrict__ v_w,
    const float* __restrict__ upd_w1, const float* __restrict__ upd_b1,
    const float* __restrict__ upd_w2, const float* __restrict__ upd_b2,
    const int* __restrict__ ngi, float* __restrict__ gs){
    __shared__ float svT[SS*NB];     // phase A: sv ; after sync: h
    __shared__ float xT[2*SS*NB];    // rows 0..127 Vnorm, 128..255 state
    __shared__ float red[2*NB];
    __shared__ float dL[NB];
    __shared__ int   gIdx[NB];
    int t  = threadIdx.x;
    int b  = t & 7, q = t >> 3, c0 = q*8;
    int n0 = blockIdx.x * NB;

    if (t < NB) gIdx[t] = ngi[n0 + t];
    for (int idx = t; idx < NB*SS; idx += 128){
        int bb = idx >> 7, s = idx & (SS-1);
        svT[lidx(s, bb)]      = sv[(n0+bb)*SS + s];
        xT[lidx(SS+s, bb)]    = state[(n0+bb)*SS + s];
    }
    __syncthreads();

    // Phase A: U = sv@u_w, V = sv@v_w for (node b, channels c0..c0+7)
    float accU[8], accV[8];
    #pragma unroll
    for (int k = 0; k < 8; k++){ accU[k] = 0.f; accV[k] = 0.f; }
    #pragma unroll 4
    for (int i = 0; i < SS; i++){
        float xv = svT[lidx(i, b)];
        float wu[8], wv[8];
        *(float4*)&wu[0] = *(const float4*)(u_w + i*SS + c0);
        *(float4*)&wu[4] = *(const float4*)(u_w + i*SS + c0 + 4);
        *(float4*)&wv[0] = *(const float4*)(v_w + i*SS + c0);
        *(float4*)&wv[4] = *(const float4*)(v_w + i*SS + c0 + 4);
        #pragma unroll
        for (int k = 0; k < 8; k++){
            accU[k] = fmaf(xv, wu[k], accU[k]);
            accV[k] = fmaf(xv, wv[k], accV[k]);
        }
    }

    // d[b] = sum_c U_c V_c : per-thread partial, reduce over q-groups
    float pd = 0.f;
    #pragma unroll
    for (int k = 0; k < 8; k++) pd = fmaf(accU[k], accV[k], pd);
    pd += __shfl_xor(pd, 8);
    pd += __shfl_xor(pd, 16);
    pd += __shfl_xor(pd, 32);
    if ((t & 63) < NB) red[(t >> 6)*NB + b] = pd;

    // Vnorm = sqrt(3 V^2) = sqrt3*|V| into xT rows 0..127
    const float SQ3 = 1.7320508075688772f;
    #pragma unroll
    for (int k = 0; k < 8; k++) xT[lidx(c0+k, b)] = SQ3 * fabsf(accV[k]);
    __syncthreads();
    if (t < NB) dL[t] = red[t] + red[NB + t];

    // Phase B: h = silu(x @ upd_w1 + b1), x = [Vnorm, state] (256-long)
    float accH[8];
    #pragma unroll
    for (int k = 0; k < 8; k++) accH[k] = 0.f;
    #pragma unroll 4
    for (int i = 0; i < 2*SS; i++){
        float xv = xT[lidx(i, b)];
        float w[8];
        *(float4*)&w[0] = *(const float4*)(upd_w1 + i*SS + c0);
        *(float4*)&w[4] = *(const float4*)(upd_w1 + i*SS + c0 + 4);
        #pragma unroll
        for (int k = 0; k < 8; k++) accH[k] = fmaf(xv, w[k], accH[k]);
    }
    {
        float bb1[8];
        *(float4*)&bb1[0] = *(const float4*)(upd_b1 + c0);
        *(float4*)&bb1[4] = *(const float4*)(upd_b1 + c0 + 4);
        #pragma unroll
        for (int k = 0; k < 8; k++)
            svT[lidx(c0+k, b)] = silu_f(accH[k] + bb1[k]);   // h (svT reuse)
    }
    __syncthreads();

    // Phase C: a_sv (w2 cols S..2S), a_ss (cols 2S..3S)
    float a2[8], a3[8];
    #pragma unroll
    for (int k = 0; k < 8; k++){ a2[k] = 0.f; a3[k] = 0.f; }
    #pragma unroll 4
    for (int j = 0; j < SS; j++){
        float hx = svT[lidx(j, b)];
        float w2a[8], w3a[8];
        *(float4*)&w2a[0] = *(const float4*)(upd_w2 + j*3*SS + SS + c0);
        *(float4*)&w2a[4] = *(const float4*)(upd_w2 + j*3*SS + SS + c0 + 4);
        *(float4*)&w3a[0] = *(const float4*)(upd_w2 + j*3*SS + 2*SS + c0);
        *(float4*)&w3a[4] = *(const float4*)(upd_w2 + j*3*SS + 2*SS + c0 + 4);
        #pragma unroll
        for (int k = 0; k < 8; k++){
            a2[k] = fmaf(hx, w2a[k], a2[k]);
            a3[k] = fmaf(hx, w3a[k], a3[k]);
        }
    }
    float dlb = dL[b];
    int   g   = gIdx[b];
    float bsv[8], bss[8];
    *(float4*)&bsv[0] = *(const float4*)(upd_b2 + SS   + c0);
    *(float4*)&bsv[4] = *(const float4*)(upd_b2 + SS   + c0 + 4);
    *(float4*)&bss[0] = *(const float4*)(upd_b2 + 2*SS + c0);
    *(float4*)&bss[4] = *(const float4*)(upd_b2 + 2*SS + c0 + 4);
    #pragma unroll
    for (int k = 0; k < 8; k++){
        float ns = (a3[k] + bss[k]) + 3.0f*dlb*(a2[k] + bsv[k]);
        atomicAdd(&gs[g*SS + c0 + k], ns);
    }
}

// ---------------------------------------------------------------------------
// Kernel 4: readout per graph
// ---------------------------------------------------------------------------
__global__ __launch_bounds__(128) void k_out(
    const float* __restrict__ gs,
    const float* __restrict__ w1, const float* __restrict__ b1,
    const float* __restrict__ w2, const float* __restrict__ b2,
    float* __restrict__ out){
    __shared__ float gsL[SS];
    __shared__ float red[2];
    int g = blockIdx.x, t = threadIdx.x;
    gsL[t] = gs[g*SS + t];
    __syncthreads();
    float acc = b1[t];
    for (int s = 0; s < SS; s++) acc = fmaf(gsL[s], w1[s*SS + t], acc);
    float p = silu_f(acc) * w2[t];
    for (int off = 32; off; off >>= 1) p += __shfl_down(p, off);
    if ((t & 63) == 0) red[t >> 6] = p;
    __syncthreads();
    if (t == 0) out[g] = red[0] + red[1] + b2[0];
}

extern "C" void kernel_launch(void* const* d_in, const int* in_sizes, int n_in,
                              void* d_out, int out_size, void* d_ws, size_t ws_size,
                              hipStream_t stream) {
    const float* evd     = (const float*)d_in[0];
    const float* elen    = (const float*)d_in[1];
    const int*   nfrom   = (const int*)  d_in[2];
    const int*   ngi     = (const int*)  d_in[3];
    // d_in[4] = num_graphs (device scalar) — G=64 fixed by setup
    const float* emb0    = (const float*)d_in[5];
    const float* phi_w1  = (const float*)d_in[6];
    const float* phi_b1  = (const float*)d_in[7];
    const float* phi_w2  = (const float*)d_in[8];
    const float* phi_b2  = (const float*)d_in[9];
    const float* filt_w  = (const float*)d_in[10];
    const float* filt_b  = (const float*)d_in[11];
    const float* u_w     = (const float*)d_in[12];
    const float* v_w     = (const float*)d_in[13];
    const float* upd_w1  = (const float*)d_in[14];
    const float* upd_b1  = (const float*)d_in[15];
    const float* upd_w2  = (const float*)d_in[16];
    const float* upd_b2  = (const float*)d_in[17];
    const float* out_w1  = (const float*)d_in[18];
    const float* out_b1  = (const float*)d_in[19];
    const float* out_w2  = (const float*)d_in[20];
    const float* out_b2  = (const float*)d_in[21];

    float* ws    = (float*)d_ws;
    float* phiW  = ws;                       // 384 (pad to 512)
    float* state = ws + 512;                 // N*S
    float* sv    = state + NN*SS;            // N*S
    float* gs    = sv + NN*SS;               // G*S

    k_phi<<<1, 128, 0, stream>>>(emb0, phi_w1, phi_b1, phi_w2, phi_b2, phiW, gs);
    k_edge<<<NN, 128, 0, stream>>>(evd, elen, nfrom, filt_w, filt_b, phiW, state, sv);
    k_update<<<NN/NB, 128, 0, stream>>>(state, sv, u_w, v_w,
                                        upd_w1, upd_b1, upd_w2, upd_b2, ngi, gs);
    k_out<<<GG, 128, 0, stream>>>(gs, out_w1, out_b1, out_w2, out_b2, (float*)d_out);
}

// Round 3
// 184.155 us; speedup vs baseline: 1.6214x; 1.6214x over previous
//
#include <hip/hip_runtime.h>
#include <math.h>

#define NN   10000
#define DEG  16
#define SS   128
#define NRBF 20
#define GG   64
#define RC   10.0f
#define PI_F 3.14159265358979323846f
#define NB   8

__device__ __forceinline__ float silu_f(float x){
    return x / (1.0f + __expf(-x));
}

// ---------------------------------------------------------------------------
// Kernel 1a: h = silu(s0 @ phi_w1 + b1)  (s0 uniform). Also zeroes gs.
// 256 threads, split-K 2-way so the 64KB w1 cold fetch has 2x parallelism.
// ---------------------------------------------------------------------------
__global__ __launch_bounds__(256) void k_phi1(
    const float* __restrict__ emb0,
    const float* __restrict__ w1, const float* __restrict__ b1,
    float* __restrict__ phiH, float* __restrict__ gs){
    __shared__ float s0[SS];
    __shared__ float part[2][SS];
    int t = threadIdx.x;
    for (int i = t; i < GG*SS; i += 256) gs[i] = 0.0f;
    if (t < SS) s0[t] = 128.0f * emb0[t];
    __syncthreads();
    int c = t & 127, half = t >> 7;
    float acc = 0.0f;
    int s0i = half * 64;
    #pragma unroll 8
    for (int s = 0; s < 64; s++)
        acc = fmaf(s0[s0i + s], w1[(s0i + s)*SS + c], acc);
    part[half][c] = acc;
    __syncthreads();
    if (t < SS) phiH[t] = silu_f(b1[t] + part[0][t] + part[1][t]);
}

// ---------------------------------------------------------------------------
// Kernel 1b: phiW = h @ phi_w2 + b2. 12 blocks x 128 threads; each block
// does 32 output channels with split-K 4-way -> 196KB w2 fetched with
// 24-wave parallelism instead of 2.
// ---------------------------------------------------------------------------
__global__ __launch_bounds__(128) void k_phi2(
    const float* __restrict__ phiH,
    const float* __restrict__ w2, const float* __restrict__ b2,
    float* __restrict__ phiW){
    __shared__ float hL[SS];
    __shared__ float part[4][32];
    int t = threadIdx.x;
    hL[t] = phiH[t];
    __syncthreads();
    int c  = blockIdx.x*32 + (t & 31);
    int kk = t >> 5;
    float acc = 0.0f;
    int sbase = kk * 32;
    #pragma unroll 8
    for (int s = 0; s < 32; s++)
        acc = fmaf(hL[sbase + s], w2[(sbase + s)*3*SS + c], acc);
    part[kk][t & 31] = acc;
    __syncthreads();
    if (t < 32){
        int cc = blockIdx.x*32 + t;
        phiW[cc] = b2[cc] + part[0][t] + part[1][t] + part[2][t] + part[3][t];
    }
}

// ---------------------------------------------------------------------------
// Kernel 2: per-node edge processing. Block n handles edges [16n, 16n+16).
// 128 threads; thread t computes BOTH channel 128+t (m2 -> state) and
// channel 256+t (m3 -> sv), sharing the rbf LDS reads between them.
// Channels 0..S (m1) are skipped: state_vec is zero at round 0.
// ---------------------------------------------------------------------------
__global__ __launch_bounds__(128) void k_edge(
    const float* __restrict__ evd, const float* __restrict__ elen,
    const int* __restrict__ node_from,
    const float* __restrict__ filt_w, const float* __restrict__ filt_b,
    const float* __restrict__ phiW,
    float* __restrict__ state, float* __restrict__ sv){
    __shared__ float rS[DEG];            // r_safe
    __shared__ float mcL[DEG];           // mask * cutoff
    __shared__ float frL[DEG];           // mask * r^2
    __shared__ float eV[DEG][3];
    __shared__ float rbfL[DEG][NRBF];    // 80B rows, 16B aligned
    __shared__ float invD;
    int n = blockIdx.x;
    int t = threadIdx.x;

    if (t < DEG){
        int e = n*DEG + t;
        float x = evd[3*e+0], y = evd[3*e+1], z = evd[3*e+2];
        float r = sqrtf(x*x + y*y + z*z);
        float len  = elen[e];
        float mask = (fabsf(len) <= RC) ? 1.0f : 0.0f;
        float cut  = (r < RC) ? 0.5f*(cosf(PI_F*r*(1.0f/RC)) + 1.0f) : 0.0f;
        rS[t]  = fmaxf(r, 1e-12f);
        mcL[t] = mask * cut;
        frL[t] = mask * r * r;
        eV[t][0] = x; eV[t][1] = y; eV[t][2] = z;
    }
    __syncthreads();
    for (int idx = t; idx < DEG*NRBF; idx += 128){
        int e = idx / NRBF, k = idx % NRBF;
        float rs = rS[e];
        rbfL[e][k] = sinf((float)(k+1) * (PI_F/RC) * rs) / rs;
    }
    if (t == 0){
        float s = 0.0f;
        for (int e = 0; e < DEG; e++) s += frL[e];
        float fbn = sqrtf(s);
        invD = (fbn > 0.0f) ? 1.0f/fbn : 1.0f;
    }
    __syncthreads();

    int gc1 = SS + t;      // m2 channel
    int gc2 = 2*SS + t;    // m3 channel
    float fw1[NRBF], fw2[NRBF];
    #pragma unroll
    for (int k = 0; k < NRBF; k++){
        fw1[k] = filt_w[k*(3*SS) + gc1];
        fw2[k] = filt_w[k*(3*SS) + gc2];
    }
    float fb1 = filt_b[gc1], fb2 = filt_b[gc2];
    float ph1 = phiW[gc1],   ph2 = phiW[gc2];
    float iD  = invD;
    int   s3  = t % 3;

    float acc1 = 0.0f, acc2 = 0.0f;
    for (int e = 0; e < DEG; e++){
        float mc = mcL[e];
        if (mc == 0.0f) continue;   // wave-uniform skip (mask=0 or r>=RC)
        const float4* rv = (const float4*)(&rbfL[e][0]);
        float4 r0 = rv[0], r1 = rv[1], r2 = rv[2], r3 = rv[3], r4 = rv[4];
        float rr[20] = {r0.x,r0.y,r0.z,r0.w, r1.x,r1.y,r1.z,r1.w,
                        r2.x,r2.y,r2.z,r2.w, r3.x,r3.y,r3.z,r3.w,
                        r4.x,r4.y,r4.z,r4.w};
        float w1 = fb1, w2 = fb2;
        #pragma unroll
        for (int k = 0; k < NRBF; k++){
            w1 = fmaf(rr[k], fw1[k], w1);
            w2 = fmaf(rr[k], fw2[k], w2);
        }
        acc1 = fmaf(ph1*mc, w1, acc1);
        acc2 = fmaf(ph2*mc*eV[e][s3]*iD, w2, acc2);
    }
    int nf = node_from[n*DEG];
    state[nf*SS + t] = acc1;
    sv[nf*SS + t]    = acc2;
}

// ---------------------------------------------------------------------------
// Kernel 3: per-node update, NB=8 nodes per 128-thread block.
// (round-1 proven version: thread = channel, coalesced 4B weight loads,
//  x-operands via LDS float4 broadcasts)
// ---------------------------------------------------------------------------
__global__ __launch_bounds__(128) void k_update(
    const float* __restrict__ state, const float* __restrict__ sv,
    const float* __restrict__ u_w, const float* __restrict__ v_w,
    const float* __restrict__ upd_w1, const float* __restrict__ upd_b1,
    const float* __restrict__ upd_w2, const float* __restrict__ upd_b2,
    const int* __restrict__ ngi, float* __restrict__ gs){
    __shared__ float svT[SS][NB];     // [s][b]
    __shared__ float xT[2*SS][NB];    // [i][b]: i<SS -> Vnorm, i>=SS -> state
    __shared__ float h2T[SS][NB];
    __shared__ float red[2][NB];
    __shared__ float dL[NB];
    int t  = threadIdx.x;
    int n0 = blockIdx.x * NB;

    for (int idx = t; idx < NB*SS; idx += 128){
        int b = idx >> 7, s = idx & (SS-1);
        svT[s][b]     = sv[(n0+b)*SS + s];
        xT[SS+s][b]   = state[(n0+b)*SS + s];
    }
    __syncthreads();

    float accU[NB], accV[NB];
    #pragma unroll
    for (int b = 0; b < NB; b++){ accU[b]=0.f; accV[b]=0.f; }
    for (int s = 0; s < SS; s++){
        float wu = u_w[s*SS + t];
        float wv = v_w[s*SS + t];
        const float4* sp = (const float4*)(&svT[s][0]);
        float4 s03 = sp[0], s47 = sp[1];
        float svv[NB] = {s03.x,s03.y,s03.z,s03.w,s47.x,s47.y,s47.z,s47.w};
        #pragma unroll
        for (int b = 0; b < NB; b++){
            accU[b] = fmaf(svv[b], wu, accU[b]);
            accV[b] = fmaf(svv[b], wv, accV[b]);
        }
    }

    int lane = t & 63, wid = t >> 6;
    #pragma unroll
    for (int b = 0; b < NB; b++){
        float p = accU[b]*accV[b];
        for (int off = 32; off; off >>= 1) p += __shfl_down(p, off);
        if (lane == 0) red[wid][b] = p;
    }
    {   // Vnorm = sqrt(V0^2+V1^2+V2^2) with V0=V1=V2 -> sqrt(3 v^2)
        float4 q0, q1;
        q0.x = sqrtf(3.f*accV[0]*accV[0]); q0.y = sqrtf(3.f*accV[1]*accV[1]);
        q0.z = sqrtf(3.f*accV[2]*accV[2]); q0.w = sqrtf(3.f*accV[3]*accV[3]);
        q1.x = sqrtf(3.f*accV[4]*accV[4]); q1.y = sqrtf(3.f*accV[5]*accV[5]);
        q1.z = sqrtf(3.f*accV[6]*accV[6]); q1.w = sqrtf(3.f*accV[7]*accV[7]);
        ((float4*)(&xT[t][0]))[0] = q0;
        ((float4*)(&xT[t][0]))[1] = q1;
    }
    __syncthreads();
    if (t < NB) dL[t] = red[0][t] + red[1][t];

    float accH[NB];
    #pragma unroll
    for (int b = 0; b < NB; b++) accH[b] = 0.f;
    for (int i = 0; i < 2*SS; i++){
        float w = upd_w1[i*SS + t];
        const float4* xp = (const float4*)(&xT[i][0]);
        float4 x03 = xp[0], x47 = xp[1];
        float xv[NB] = {x03.x,x03.y,x03.z,x03.w,x47.x,x47.y,x47.z,x47.w};
        #pragma unroll
        for (int b = 0; b < NB; b++) accH[b] = fmaf(xv[b], w, accH[b]);
    }
    float b1v = upd_b1[t];
    {
        float4 q0, q1;
        q0.x = silu_f(accH[0]+b1v); q0.y = silu_f(accH[1]+b1v);
        q0.z = silu_f(accH[2]+b1v); q0.w = silu_f(accH[3]+b1v);
        q1.x = silu_f(accH[4]+b1v); q1.y = silu_f(accH[5]+b1v);
        q1.z = silu_f(accH[6]+b1v); q1.w = silu_f(accH[7]+b1v);
        ((float4*)(&h2T[t][0]))[0] = q0;
        ((float4*)(&h2T[t][0]))[1] = q1;
    }
    __syncthreads();

    float a1[NB], a2[NB];
    #pragma unroll
    for (int b = 0; b < NB; b++){ a1[b]=0.f; a2[b]=0.f; }
    for (int j = 0; j < SS; j++){
        float w1 = upd_w2[j*3*SS + SS   + t];   // a_sv channel
        float w2 = upd_w2[j*3*SS + 2*SS + t];   // a_ss channel
        const float4* hp = (const float4*)(&h2T[j][0]);
        float4 h03 = hp[0], h47 = hp[1];
        float hv[NB] = {h03.x,h03.y,h03.z,h03.w,h47.x,h47.y,h47.z,h47.w};
        #pragma unroll
        for (int b = 0; b < NB; b++){
            a1[b] = fmaf(hv[b], w1, a1[b]);
            a2[b] = fmaf(hv[b], w2, a2[b]);
        }
    }
    float bsv = upd_b2[SS+t], bss = upd_b2[2*SS+t];
    #pragma unroll
    for (int b = 0; b < NB; b++){
        float ns = (a2[b] + bss) + 3.0f*dL[b]*(a1[b] + bsv);
        int g = ngi[n0+b];
        atomicAdd(&gs[g*SS + t], ns);
    }
}

// ---------------------------------------------------------------------------
// Kernel 4: readout per graph
// ---------------------------------------------------------------------------
__global__ __launch_bounds__(128) void k_out(
    const float* __restrict__ gs,
    const float* __restrict__ w1, const float* __restrict__ b1,
    const float* __restrict__ w2, const float* __restrict__ b2,
    float* __restrict__ out){
    __shared__ float gsL[SS];
    __shared__ float red[2];
    int g = blockIdx.x, t = threadIdx.x;
    gsL[t] = gs[g*SS + t];
    __syncthreads();
    float acc = b1[t];
    #pragma unroll 4
    for (int s = 0; s < SS; s++) acc = fmaf(gsL[s], w1[s*SS + t], acc);
    float p = silu_f(acc) * w2[t];
    for (int off = 32; off; off >>= 1) p += __shfl_down(p, off);
    if ((t & 63) == 0) red[t >> 6] = p;
    __syncthreads();
    if (t == 0) out[g] = red[0] + red[1] + b2[0];
}

extern "C" void kernel_launch(void* const* d_in, const int* in_sizes, int n_in,
                              void* d_out, int out_size, void* d_ws, size_t ws_size,
                              hipStream_t stream) {
    const float* evd     = (const float*)d_in[0];
    const float* elen    = (const float*)d_in[1];
    const int*   nfrom   = (const int*)  d_in[2];
    const int*   ngi     = (const int*)  d_in[3];
    // d_in[4] = num_graphs (device scalar) — G=64 fixed by setup
    const float* emb0    = (const float*)d_in[5];
    const float* phi_w1  = (const float*)d_in[6];
    const float* phi_b1  = (const float*)d_in[7];
    const float* phi_w2  = (const float*)d_in[8];
    const float* phi_b2  = (const float*)d_in[9];
    const float* filt_w  = (const float*)d_in[10];
    const float* filt_b  = (const float*)d_in[11];
    const float* u_w     = (const float*)d_in[12];
    const float* v_w     = (const float*)d_in[13];
    const float* upd_w1  = (const float*)d_in[14];
    const float* upd_b1  = (const float*)d_in[15];
    const float* upd_w2  = (const float*)d_in[16];
    const float* upd_b2  = (const float*)d_in[17];
    const float* out_w1  = (const float*)d_in[18];
    const float* out_b1  = (const float*)d_in[19];
    const float* out_w2  = (const float*)d_in[20];
    const float* out_b2  = (const float*)d_in[21];

    float* ws    = (float*)d_ws;
    float* phiW  = ws;                       // 384 (pad to 512)
    float* state = ws + 512;                 // N*S
    float* sv    = state + NN*SS;            // N*S
    float* gs    = sv + NN*SS;               // G*S
    float* phiH  = gs + GG*SS;               // 128

    k_phi1<<<1, 256, 0, stream>>>(emb0, phi_w1, phi_b1, phiH, gs);
    k_phi2<<<12, 128, 0, stream>>>(phiH, phi_w2, phi_b2, phiW);
    k_edge<<<NN, 128, 0, stream>>>(evd, elen, nfrom, filt_w, filt_b, phiW, state, sv);
    k_update<<<NN/NB, 128, 0, stream>>>(state, sv, u_w, v_w,
                                        upd_w1, upd_b1, upd_w2, upd_b2, ngi, gs);
    k_out<<<GG, 128, 0, stream>>>(gs, out_w1, out_b1, out_w2, out_b2, (float*)d_out);
}